// Round 16
// baseline (2185.777 us; speedup 1.0000x reference)
//
#include <hip/hip_runtime.h>

#define NN 50000
#define NH 100000
#define NI 600000
#define FIN 512
#define HID 128
#define LNEPS 1e-5f

static __device__ __forceinline__ void fma4(float4& a, float s, const float4& w) {
  a.x += s * w.x; a.y += s * w.y; a.z += s * w.z; a.w += s * w.w;
}
static __device__ __forceinline__ float f4c(const float4& a, int k) {
  return k == 0 ? a.x : k == 1 ? a.y : k == 2 ? a.z : a.w;
}

// ============================ CSR build (both branches per launch) ============================
__global__ void k_hist2(const int* __restrict__ i1, const int* __restrict__ i2, int n,
                        int* __restrict__ d1, int* __restrict__ d2) {
  int nb = gridDim.x >> 1, blk = blockIdx.x;
  bool a = blk < nb;
  const int* idx = a ? i1 : i2;
  int* deg = a ? d1 : d2;
  int i = (a ? blk : blk - nb) * 256 + threadIdx.x;
  if (i < n) atomicAdd(&deg[idx[i]], 1);
}

__global__ __launch_bounds__(1024) void k_scan1_2(int* __restrict__ dd1, int* __restrict__ dd2,
                                                  int m, int* __restrict__ b1,
                                                  int* __restrict__ b2) {
  __shared__ int sh[1024];
  int nb = gridDim.x >> 1, blk = blockIdx.x;
  bool a = blk < nb;
  int* data = a ? dd1 : dd2;
  int* bsums = a ? b1 : b2;
  int lb = a ? blk : blk - nb;
  int tid = threadIdx.x;
  int i = lb * 1024 + tid;
  int v = (i < m) ? data[i] : 0;
  sh[tid] = v;
  __syncthreads();
  for (int off = 1; off < 1024; off <<= 1) {
    int tv = (tid >= off) ? sh[tid - off] : 0;
    __syncthreads();
    sh[tid] += tv;
    __syncthreads();
  }
  if (i < m) data[i] = sh[tid] - v;  // exclusive
  if (tid == 1023) bsums[lb] = sh[1023];
}

__global__ __launch_bounds__(1024) void k_scan2_2(int* __restrict__ b1, int* __restrict__ b2,
                                                  int nb) {
  __shared__ int sh[1024];
  int* bsums = blockIdx.x == 0 ? b1 : b2;
  int tid = threadIdx.x;
  int v = (tid < nb) ? bsums[tid] : 0;
  sh[tid] = v;
  __syncthreads();
  for (int off = 1; off < 1024; off <<= 1) {
    int tv = (tid >= off) ? sh[tid - off] : 0;
    __syncthreads();
    sh[tid] += tv;
    __syncthreads();
  }
  if (tid < nb) bsums[tid] = sh[tid] - v;
}

__global__ void k_scan3_2(int* __restrict__ dd1, int* __restrict__ dd2,
                          const int* __restrict__ b1, const int* __restrict__ b2,
                          int m, int total) {
  int nb = gridDim.x >> 1, blk = blockIdx.x;
  bool a = blk < nb;
  int* data = a ? dd1 : dd2;
  const int* bs = a ? b1 : b2;
  int i = (a ? blk : blk - nb) * 256 + threadIdx.x;
  if (i < m) data[i] += bs[i >> 10];
  if (i == 0) data[m] = total;
}

__global__ void k_fill2(const int* __restrict__ k1, const int* __restrict__ o1,
                        const int* __restrict__ k2, const int* __restrict__ o2, int n,
                        const int* __restrict__ s1, const int* __restrict__ s2,
                        int* __restrict__ c1, int* __restrict__ c2,
                        int* __restrict__ out1, int* __restrict__ out2) {
  int nb = gridDim.x >> 1, blk = blockIdx.x;
  bool a = blk < nb;
  const int* key = a ? k1 : k2;
  const int* oth = a ? o1 : o2;
  const int* st = a ? s1 : s2;
  int* cur = a ? c1 : c2;
  int* out = a ? out1 : out2;
  int i = (a ? blk : blk - nb) * 256 + threadIdx.x;
  if (i >= n) return;
  int k = key[i];
  int pos = st[k] + atomicAdd(&cur[k], 1);
  out[pos] = oth[i];
}

// Sort each CSR segment ascending -> deterministic order every replay.
__global__ void k_sort2(const int* __restrict__ s1, const int* __restrict__ s2, int nseg,
                        int* __restrict__ v1, int* __restrict__ v2) {
  int nb = gridDim.x >> 1, blk = blockIdx.x;
  bool a = blk < nb;
  const int* starts = a ? s1 : s2;
  int* vals = a ? v1 : v2;
  int seg = (a ? blk : blk - nb) * 256 + threadIdx.x;
  if (seg >= nseg) return;
  int s = starts[seg], e = starts[seg + 1];
  int d = e - s;
  if (d <= 1) return;
  if (d <= 48) {
    int buf[48];
    for (int i = 0; i < d; i++) buf[i] = vals[s + i];
    for (int i = 1; i < d; i++) {
      int key = buf[i], j = i - 1;
      while (j >= 0 && buf[j] > key) { buf[j + 1] = buf[j]; j--; }
      buf[j + 1] = key;
    }
    for (int i = 0; i < d; i++) vals[s + i] = buf[i];
  } else {
    for (int i = s + 1; i < e; i++) {
      int key = vals[i], j = i - 1;
      while (j >= s && vals[j] > key) { vals[j + 1] = vals[j]; j--; }
      vals[j + 1] = key;
    }
  }
}

// ============================ W2 precompute ============================
__global__ void k_prep_w2g(const float* __restrict__ W2, const float* __restrict__ g2,
                           float* __restrict__ W2g) {
  int i = blockIdx.x * 256 + threadIdx.x;
  if (i >= 256 * 128) return;
  int k = i >> 7;
  W2g[i] = g2[k] * W2[i];
}

__global__ __launch_bounds__(128) void k_prep_sgc0(
    const float* __restrict__ W2, const float* __restrict__ g2,
    const float* __restrict__ b2, const float* __restrict__ bias2,
    float* __restrict__ s_g, float* __restrict__ c0) {
  int t = threadIdx.x;
  float sg = 0.f, cc = 0.f;
  for (int k = 0; k < 256; k++) {
    float w = W2[k * 128 + t];
    sg += g2[k] * w;
    cc += b2[k] * w;
  }
  s_g[t] = sg;
  c0[t] = cc + bias2[t];
}

// ============================ GEMM primitives ============================
// Ash: 32x128 A tile (stride 132). W is read DIRECTLY from global (L1/L2-resident
// broadcast operand: per wave only 16 distinct 16B addrs per half, 4-way lane share).
// Thread (tc=t&15, tr=t>>4): rows tr*2..+1, cols {tc*4..+3, 64+tc*4..+3}.
// No internal W staging -> no per-stage barriers; entry barrier protects Ash writes.
static __device__ __forceinline__ void gemm128(const float (*Ash)[132],
                                               const float* __restrict__ W,
                                               int tc, int tr,
                                               float4 acc0[2], float4 acc1[2]) {
  __syncthreads();  // Ash writes visible to all waves before reads
  const float* Wp0 = W + tc * 4;
  const float* Wp1 = W + 64 + tc * 4;
  for (int kk = 0; kk < 8; kk++) {
    const int kb = kk * 16;
#pragma unroll
    for (int k4 = 0; k4 < 16; k4 += 4) {
      float4 a0 = *(const float4*)&Ash[tr * 2 + 0][kb + k4];
      float4 a1 = *(const float4*)&Ash[tr * 2 + 1][kb + k4];
#pragma unroll
      for (int kk2 = 0; kk2 < 4; kk2++) {
        size_t krow = (size_t)(kb + k4 + kk2) * 128;
        float4 w0 = *(const float4*)(Wp0 + krow);
        float4 w1 = *(const float4*)(Wp1 + krow);
        float a0v = f4c(a0, kk2), a1v = f4c(a1, kk2);
        fma4(acc0[0], a0v, w0); fma4(acc0[1], a0v, w1);
        fma4(acc1[0], a1v, w0); fma4(acc1[1], a1v, w1);
      }
    }
  }
}

// Legacy 64-col-half LDS core (kept for the 64-col classifier GEMM).
static __device__ __forceinline__ void stage_w(float (*Wsh)[68], const float* __restrict__ W,
                                               int ldw, int row0, int col0, int t) {
  for (int s = t; s < 512; s += 256) {
    int k = s >> 4, c4 = (s & 15) * 4;
    *(float4*)&Wsh[k][c4] = *(const float4*)(W + (size_t)(row0 + k) * ldw + col0 + c4);
  }
}

static __device__ __forceinline__ void inner32(const float (*Ash)[132], const float (*Wsh)[68],
                                               int kb, int tc, int tr,
                                               float4& acc0, float4& acc1) {
#pragma unroll
  for (int k = 0; k < 32; k += 4) {
    float4 w0 = *(const float4*)&Wsh[k + 0][tc * 4];
    float4 w1 = *(const float4*)&Wsh[k + 1][tc * 4];
    float4 w2 = *(const float4*)&Wsh[k + 2][tc * 4];
    float4 w3 = *(const float4*)&Wsh[k + 3][tc * 4];
    float4 a0 = *(const float4*)&Ash[tr * 2 + 0][kb + k];
    float4 a1 = *(const float4*)&Ash[tr * 2 + 1][kb + k];
    fma4(acc0, a0.x, w0); fma4(acc0, a0.y, w1); fma4(acc0, a0.z, w2); fma4(acc0, a0.w, w3);
    fma4(acc1, a1.x, w0); fma4(acc1, a1.y, w1); fma4(acc1, a1.z, w2); fma4(acc1, a1.w, w3);
  }
}

static __device__ __forceinline__ void load_a128(float (*Ash)[132], const float* __restrict__ A,
                                                 int r0, int N, int t) {
  for (int s = t; s < 1024; s += 256) {
    int r = s >> 5, c4 = (s & 31) * 4;
    float4 val = {0, 0, 0, 0};
    if (r0 + r < N) val = *(const float4*)(A + (size_t)(r0 + r) * 128 + c4);
    *(float4*)&Ash[r][c4] = val;
  }
}

// Load A tile scaled per-row: Ash[r][:] = scale[r0+r] * A[r0+r][:]
static __device__ __forceinline__ void load_a128s(float (*Ash)[132], const float* __restrict__ A,
                                                  const float* __restrict__ scale,
                                                  int r0, int N, int t) {
  for (int s = t; s < 1024; s += 256) {
    int r = s >> 5, c4 = (s & 31) * 4;
    float4 val = {0, 0, 0, 0};
    if (r0 + r < N) {
      float sc = scale[r0 + r];
      float4 x = *(const float4*)(A + (size_t)(r0 + r) * 128 + c4);
      val.x = sc * x.x; val.y = sc * x.y; val.z = sc * x.z; val.w = sc * x.w;
    }
    *(float4*)&Ash[r][c4] = val;
  }
}

// LN rows of Ash in place (stats optional), 4 waves x 8 rows (wave-local rows).
template <bool STATS>
static __device__ __forceinline__ void ln_tile(float (*Ash)[132], const float* __restrict__ g,
                                               const float* __restrict__ b,
                                               float* __restrict__ sn, float* __restrict__ qn,
                                               int r0, int N, int t) {
  int wv = t >> 6, lane = t & 63;
  for (int j = 0; j < 8; j++) {
    int r = wv * 8 + j;
    if (r0 + r < N) {
      float2 x = *(float2*)&Ash[r][lane * 2];
      float s = x.x + x.y, sq = x.x * x.x + x.y * x.y;
      for (int m = 1; m < 64; m <<= 1) { s += __shfl_xor(s, m); sq += __shfl_xor(sq, m); }
      if (STATS && lane == 0) { sn[r0 + r] = s; qn[r0 + r] = sq; }
      float mu = s * (1.f / 128.f);
      float var = sq * (1.f / 128.f) - mu * mu;
      float rstd = rsqrtf(var + LNEPS);
      float2 gg = ((const float2*)g)[lane];
      float2 bb = ((const float2*)b)[lane];
      float2 o;
      o.x = (x.x - mu) * rstd * gg.x + bb.x;
      o.y = (x.y - mu) * rstd * gg.y + bb.y;
      *(float2*)&Ash[r][lane * 2] = o;
    }
  }
}

// ============================ proj + relu + LN-stats + W1 GEMM ============================
__global__ __launch_bounds__(256) void k_proj_fused(
    const float* __restrict__ x_in, const float* __restrict__ lin_w,
    const float* __restrict__ lin_b, const float* __restrict__ w1g,
    const float* __restrict__ w1bn, const float* __restrict__ w1w,
    const float* __restrict__ w1b, float* __restrict__ X0,
    float* __restrict__ B, float* __restrict__ sn, float* __restrict__ qn, int N) {
  __shared__ float Ash[32][132];
  const int t = threadIdx.x;
  const int r0 = blockIdx.x * 32;
  const int tc = t & 15, tr = t >> 4;
  float4 acc0[2] = {{0,0,0,0},{0,0,0,0}}, acc1[2] = {{0,0,0,0},{0,0,0,0}};
  for (int kq = 0; kq < 4; kq++) {
    __syncthreads();  // prior gemm128 Ash reads done
    for (int s = t; s < 1024; s += 256) {
      int r = s >> 5, c4 = (s & 31) * 4;
      float4 val = {0, 0, 0, 0};
      if (r0 + r < N) val = *(const float4*)(x_in + (size_t)(r0 + r) * 512 + kq * 128 + c4);
      *(float4*)&Ash[r][c4] = val;
    }
    gemm128((const float(*)[132])Ash, lin_w + (size_t)kq * 128 * 128, tc, tr, acc0, acc1);
  }
  __syncthreads();
  for (int h = 0; h < 2; h++) {
    int c = h * 64 + tc * 4;
    float4 bb = *(const float4*)(lin_b + c);
    int row0 = r0 + tr * 2;
    float4 z0, z1;
    z0.x = fmaxf(acc0[h].x + bb.x, 0.f); z0.y = fmaxf(acc0[h].y + bb.y, 0.f);
    z0.z = fmaxf(acc0[h].z + bb.z, 0.f); z0.w = fmaxf(acc0[h].w + bb.w, 0.f);
    z1.x = fmaxf(acc1[h].x + bb.x, 0.f); z1.y = fmaxf(acc1[h].y + bb.y, 0.f);
    z1.z = fmaxf(acc1[h].z + bb.z, 0.f); z1.w = fmaxf(acc1[h].w + bb.w, 0.f);
    if (row0 < N) {
      *(float4*)(X0 + (size_t)row0 * 128 + c) = z0;
      *(float4*)&Ash[tr * 2][c] = z0;
    }
    if (row0 + 1 < N) {
      *(float4*)(X0 + (size_t)(row0 + 1) * 128 + c) = z1;
      *(float4*)&Ash[tr * 2 + 1][c] = z1;
    }
  }
  __syncthreads();
  ln_tile<true>(Ash, w1g, w1bn, sn, qn, r0, N, t);
  float4 f0[2] = {{0,0,0,0},{0,0,0,0}}, f1[2] = {{0,0,0,0},{0,0,0,0}};
  gemm128((const float(*)[132])Ash, w1w, tc, tr, f0, f1);
  for (int h = 0; h < 2; h++) {
    int c = h * 64 + tc * 4;
    float4 bb = *(const float4*)(w1b + c);
    int row0 = r0 + tr * 2;
    if (row0 < N) {
      float4 o = {f0[h].x + bb.x, f0[h].y + bb.y, f0[h].z + bb.z, f0[h].w + bb.w};
      *(float4*)(B + (size_t)row0 * 128 + c) = o;
    }
    if (row0 + 1 < N) {
      float4 o = {f1[h].x + bb.x, f1[h].y + bb.y, f1[h].z + bb.z, f1[h].w + bb.w};
      *(float4*)(B + (size_t)(row0 + 1) * 128 + c) = o;
    }
  }
}

// ============================ hedge mean gather (half-wave per hedge) ============================
__global__ __launch_bounds__(256) void k_xe(
    const float* __restrict__ B, const int* __restrict__ starts,
    const int* __restrict__ vlist, float* __restrict__ Xe,
    float* __restrict__ se, float* __restrict__ qe, int M) {
  int half = threadIdx.x >> 5, lane = threadIdx.x & 31;
  int m = blockIdx.x * 8 + half;
  if (m >= M) return;
  int s = starts[m], e = starts[m + 1];
  float4 acc = {0.f, 0.f, 0.f, 0.f};
  for (int j = s; j < e; j++) {
    int vv = vlist[j];
    float4 val = ((const float4*)(B + (size_t)vv * 128))[lane];
    acc.x += val.x; acc.y += val.y; acc.z += val.z; acc.w += val.w;
  }
  int d = e - s;
  float inv = d > 0 ? 1.f / (float)d : 0.f;
  float4 o = {acc.x * inv, acc.y * inv, acc.z * inv, acc.w * inv};
  ((float4*)(Xe + (size_t)m * 128))[lane] = o;
  float ss = o.x + o.y + o.z + o.w;
  float qq = o.x * o.x + o.y * o.y + o.z * o.z + o.w * o.w;
  for (int mm = 1; mm < 32; mm <<= 1) {
    ss += __shfl_xor(ss, mm, 32);
    qq += __shfl_xor(qq, mm, 32);
  }
  if (lane == 0) { se[m] = ss; qe[m] = qq; }
}

// ============================ node gather (half-wave per node) ============================
__global__ __launch_bounds__(256) void k_nodeg(
    const float* __restrict__ Xe, const int* __restrict__ starts_v,
    const int* __restrict__ e_by_v, const float* __restrict__ sn,
    const float* __restrict__ qn, const float* __restrict__ se,
    const float* __restrict__ qe, float* __restrict__ Qb,
    float* __restrict__ suma_arr, float* __restrict__ invdeg,
    float* __restrict__ t2arr, int N) {
  int half = threadIdx.x >> 5, lane = threadIdx.x & 31;
  int v = blockIdx.x * 8 + half;
  if (v >= N) return;
  int s = starts_v[v], e = starts_v[v + 1];
  float svn = sn[v], qvn = qn[v];
  float4 acc = {0.f, 0.f, 0.f, 0.f};
  float suma = 0.f, sumb = 0.f;
  for (int j = s; j < e; j++) {
    int ee = e_by_v[j];
    float mu = (svn + se[ee]) * (1.f / 256.f);
    float e2 = (qvn + qe[ee]) * (1.f / 256.f);
    float rstd = rsqrtf(e2 - mu * mu + LNEPS);
    suma += rstd;
    sumb += mu * rstd;
    float4 vv = ((const float4*)(Xe + (size_t)ee * 128))[lane];
    acc.x += rstd * vv.x; acc.y += rstd * vv.y;
    acc.z += rstd * vv.z; acc.w += rstd * vv.w;
  }
  ((float4*)(Qb + (size_t)v * 128))[lane] = acc;
  if (lane == 0) {
    int d = e - s;
    float inv = d > 0 ? 1.f / (float)d : 0.f;
    suma_arr[v] = suma;
    invdeg[v] = inv;
    t2arr[v] = sumb * inv;
  }
}

// ======== shared conv2 body: [suma*X | Qb]@W2g + epilogue(blend) + LN(wg,wbn) into Ash ========
static __device__ __forceinline__ void conv2_body(
    float (*Ash)[132],
    const float* __restrict__ Xsrc, const float* __restrict__ suma,
    const float* __restrict__ Q, const float* __restrict__ W,
    const float* __restrict__ invdeg, const float* __restrict__ t2arr,
    const float* __restrict__ s_g, const float* __restrict__ c0,
    const float* __restrict__ X0, const float* __restrict__ wg,
    const float* __restrict__ wbn, int r0, int N, int t, int tc, int tr) {
  float4 acc0[2] = {{0,0,0,0},{0,0,0,0}}, acc1[2] = {{0,0,0,0},{0,0,0,0}};
  for (int ph = 0; ph < 2; ph++) {
    __syncthreads();  // prior gemm128 Ash reads done
    if (ph == 0) load_a128s(Ash, Xsrc, suma, r0, N, t);
    else load_a128(Ash, Q, r0, N, t);
    gemm128((const float(*)[132])Ash, W + (size_t)ph * 128 * 128, tc, tr, acc0, acc1);
  }
  __syncthreads();
  for (int r = 0; r < 2; r++) {
    int row = r0 + tr * 2 + r;
    if (row < N) {
      float t1 = invdeg[row], t2 = t2arr[row];
      float flag = t1 > 0.f ? 1.f : 0.f;
      for (int h = 0; h < 2; h++) {
        int c = h * 64 + tc * 4;
        float4 g = r ? acc1[h] : acc0[h];
        float4 sg = *(const float4*)(s_g + c);
        float4 cc = *(const float4*)(c0 + c);
        float4 x0 = *(const float4*)(X0 + (size_t)row * 128 + c);
        float4 z;
        z.x = 0.5f * (g.x * t1 - t2 * sg.x + flag * cc.x) + 0.5f * x0.x;
        z.y = 0.5f * (g.y * t1 - t2 * sg.y + flag * cc.y) + 0.5f * x0.y;
        z.z = 0.5f * (g.z * t1 - t2 * sg.z + flag * cc.z) + 0.5f * x0.z;
        z.w = 0.5f * (g.w * t1 - t2 * sg.w + flag * cc.w) + 0.5f * x0.w;
        *(float4*)&Ash[tr * 2 + r][c] = z;
      }
    }
  }
  __syncthreads();
  ln_tile<false>(Ash, wg, wbn, nullptr, nullptr, r0, N, t);
}

// ============ conv2 + W-GEMM+relu -> X ; LN-stats ; W1 GEMM -> B (layer 0) ============
__global__ __launch_bounds__(256) void k_conv2w(
    const float* __restrict__ Xsrc, const float* __restrict__ suma,
    const float* __restrict__ Q, const float* __restrict__ W,
    const float* __restrict__ invdeg, const float* __restrict__ t2arr,
    const float* __restrict__ s_g, const float* __restrict__ c0,
    const float* __restrict__ X0, const float* __restrict__ wg,
    const float* __restrict__ wbn, const float* __restrict__ Ww,
    const float* __restrict__ wb, const float* __restrict__ w1g,
    const float* __restrict__ w1bn, const float* __restrict__ w1w,
    const float* __restrict__ w1b, float* __restrict__ Xout,
    float* __restrict__ B, float* __restrict__ sn, float* __restrict__ qn, int N) {
  __shared__ float Ash[32][132];
  const int t = threadIdx.x;
  const int r0 = blockIdx.x * 32;
  const int tc = t & 15, tr = t >> 4;
  conv2_body(Ash, Xsrc, suma, Q, W, invdeg, t2arr, s_g, c0, X0, wg, wbn,
             r0, N, t, tc, tr);
  float4 b0[2] = {{0,0,0,0},{0,0,0,0}}, b1[2] = {{0,0,0,0},{0,0,0,0}};
  gemm128((const float(*)[132])Ash, Ww, tc, tr, b0, b1);
  __syncthreads();
  for (int h = 0; h < 2; h++) {
    int c = h * 64 + tc * 4;
    float4 bb = *(const float4*)(wb + c);
    int row0 = r0 + tr * 2;
    float4 z0, z1;
    z0.x = fmaxf(b0[h].x + bb.x, 0.f); z0.y = fmaxf(b0[h].y + bb.y, 0.f);
    z0.z = fmaxf(b0[h].z + bb.z, 0.f); z0.w = fmaxf(b0[h].w + bb.w, 0.f);
    z1.x = fmaxf(b1[h].x + bb.x, 0.f); z1.y = fmaxf(b1[h].y + bb.y, 0.f);
    z1.z = fmaxf(b1[h].z + bb.z, 0.f); z1.w = fmaxf(b1[h].w + bb.w, 0.f);
    if (row0 < N) {
      *(float4*)(Xout + (size_t)row0 * 128 + c) = z0;
      *(float4*)&Ash[tr * 2][c] = z0;
    }
    if (row0 + 1 < N) {
      *(float4*)(Xout + (size_t)(row0 + 1) * 128 + c) = z1;
      *(float4*)&Ash[tr * 2 + 1][c] = z1;
    }
  }
  __syncthreads();
  ln_tile<true>(Ash, w1g, w1bn, sn, qn, r0, N, t);
  float4 f0[2] = {{0,0,0,0},{0,0,0,0}}, f1[2] = {{0,0,0,0},{0,0,0,0}};
  gemm128((const float(*)[132])Ash, w1w, tc, tr, f0, f1);
  for (int h = 0; h < 2; h++) {
    int c = h * 64 + tc * 4;
    float4 bb = *(const float4*)(w1b + c);
    int row0 = r0 + tr * 2;
    if (row0 < N) {
      float4 o = {f0[h].x + bb.x, f0[h].y + bb.y, f0[h].z + bb.z, f0[h].w + bb.w};
      *(float4*)(B + (size_t)row0 * 128 + c) = o;
    }
    if (row0 + 1 < N) {
      float4 o = {f1[h].x + bb.x, f1[h].y + bb.y, f1[h].z + bb.z, f1[h].w + bb.w};
      *(float4*)(B + (size_t)(row0 + 1) * 128 + c) = o;
    }
  }
}

// ============ conv2 + W-GEMM+relu ; classifier (cw1 GEMM, LN64, dot) (layer 1) ============
__global__ __launch_bounds__(256) void k_conv2c(
    const float* __restrict__ Xsrc, const float* __restrict__ suma,
    const float* __restrict__ Q, const float* __restrict__ W,
    const float* __restrict__ invdeg, const float* __restrict__ t2arr,
    const float* __restrict__ s_g, const float* __restrict__ c0,
    const float* __restrict__ X0, const float* __restrict__ wg,
    const float* __restrict__ wbn, const float* __restrict__ Ww,
    const float* __restrict__ wb, const float* __restrict__ cw1,
    const float* __restrict__ cb1, const float* __restrict__ cg,
    const float* __restrict__ cbn, const float* __restrict__ cw2,
    const float* __restrict__ cb2, float* __restrict__ out, int N) {
  __shared__ float Ash[32][132];
  __shared__ float Wsh[32][68];
  const int t = threadIdx.x;
  const int r0 = blockIdx.x * 32;
  const int tc = t & 15, tr = t >> 4;
  conv2_body(Ash, Xsrc, suma, Q, W, invdeg, t2arr, s_g, c0, X0, wg, wbn,
             r0, N, t, tc, tr);
  float4 b0[2] = {{0,0,0,0},{0,0,0,0}}, b1[2] = {{0,0,0,0},{0,0,0,0}};
  gemm128((const float(*)[132])Ash, Ww, tc, tr, b0, b1);
  __syncthreads();
  for (int h = 0; h < 2; h++) {
    int c = h * 64 + tc * 4;
    float4 bb = *(const float4*)(wb + c);
    int row0 = r0 + tr * 2;
    if (row0 < N) {
      float4 z;
      z.x = fmaxf(b0[h].x + bb.x, 0.f); z.y = fmaxf(b0[h].y + bb.y, 0.f);
      z.z = fmaxf(b0[h].z + bb.z, 0.f); z.w = fmaxf(b0[h].w + bb.w, 0.f);
      *(float4*)&Ash[tr * 2][c] = z;
    }
    if (row0 + 1 < N) {
      float4 z;
      z.x = fmaxf(b1[h].x + bb.x, 0.f); z.y = fmaxf(b1[h].y + bb.y, 0.f);
      z.z = fmaxf(b1[h].z + bb.z, 0.f); z.w = fmaxf(b1[h].w + bb.w, 0.f);
      *(float4*)&Ash[tr * 2 + 1][c] = z;
    }
  }
  // H = relu(Z @ cw1 + cb1): 64 cols (legacy LDS core)
  float4 h0 = {0,0,0,0}, h1 = {0,0,0,0};
  for (int kc = 0; kc < 4; kc++) {
    __syncthreads();
    stage_w(Wsh, cw1, 64, kc * 32, 0, t);
    __syncthreads();
    inner32((const float(*)[132])Ash, (const float(*)[68])Wsh, kc * 32, tc, tr, h0, h1);
  }
  __syncthreads();
  {
    int c = tc * 4;
    float4 bb = *(const float4*)(cb1 + c);
    float4 z;
    z.x = fmaxf(h0.x + bb.x, 0.f); z.y = fmaxf(h0.y + bb.y, 0.f);
    z.z = fmaxf(h0.z + bb.z, 0.f); z.w = fmaxf(h0.w + bb.w, 0.f);
    *(float4*)&Wsh[tr * 2][c] = z;
    z.x = fmaxf(h1.x + bb.x, 0.f); z.y = fmaxf(h1.y + bb.y, 0.f);
    z.z = fmaxf(h1.z + bb.z, 0.f); z.w = fmaxf(h1.w + bb.w, 0.f);
    *(float4*)&Wsh[tr * 2 + 1][c] = z;
  }
  __syncthreads();
  int wv = t >> 6, lane = t & 63;
  for (int j = 0; j < 8; j++) {
    int r = wv * 8 + j;
    if (r0 + r < N) {
      float h = Wsh[r][lane];
      float s = h, sq = h * h;
      for (int m = 1; m < 64; m <<= 1) { s += __shfl_xor(s, m); sq += __shfl_xor(sq, m); }
      float mu = s * (1.f / 64.f);
      float var = sq * (1.f / 64.f) - mu * mu;
      float rstd = rsqrtf(var + LNEPS);
      float hn = (h - mu) * rstd * cg[lane] + cbn[lane];
      float c = hn * cw2[lane];
      for (int m = 1; m < 64; m <<= 1) c += __shfl_xor(c, m);
      if (lane == 0) out[r0 + r] = c + cb2[0];
    }
  }
}

// ============================ per-branch pipeline (CSR prebuilt) ============================
static void run_branch(const float* x_in,
                       const float* lin_w, const float* lin_b,
                       const float* w1g, const float* w1bn, const float* w1w, const float* w1b,
                       const float* W2g, const float* s_g, const float* c0,
                       const float* wg, const float* wbn, const float* ww, const float* wb,
                       const float* cw1, const float* cb1, const float* cg, const float* cbn,
                       const float* cw2, const float* cb2,
                       float* X, float* X0, float* B, float* Qb, float* Xe,
                       float* sn, float* qn, float* se, float* qe,
                       float* suma, float* invdeg, float* t2arr,
                       const int* starts_e, const int* starts_v,
                       const int* v_by_e, const int* e_by_v,
                       float* out, hipStream_t stream) {
  const int GN = (NN + 31) / 32;
  k_proj_fused<<<GN, 256, 0, stream>>>(x_in, lin_w, lin_b, w1g, w1bn, w1w, w1b,
                                       X0, B, sn, qn, NN);
  for (int layer = 0; layer < 2; ++layer) {
    const float* Xsrc = layer == 0 ? X0 : X;
    k_xe<<<NH / 8, 256, 0, stream>>>(B, starts_e, v_by_e, Xe, se, qe, NH);
    k_nodeg<<<(NN + 7) / 8, 256, 0, stream>>>(Xe, starts_v, e_by_v, sn, qn, se, qe,
                                              Qb, suma, invdeg, t2arr, NN);
    if (layer == 0) {
      k_conv2w<<<GN, 256, 0, stream>>>(Xsrc, suma, Qb, W2g, invdeg, t2arr, s_g, c0,
                                       X0, wg, wbn, ww, wb, w1g, w1bn, w1w, w1b,
                                       X, B, sn, qn, NN);
    } else {
      k_conv2c<<<GN, 256, 0, stream>>>(Xsrc, suma, Qb, W2g, invdeg, t2arr, s_g, c0,
                                       X0, wg, wbn, ww, wb, cw1, cb1, cg, cbn,
                                       cw2, cb2, out, NN);
    }
  }
}

extern "C" void kernel_launch(void* const* d_in, const int* in_sizes, int n_in,
                              void* d_out, int out_size, void* d_ws, size_t ws_size,
                              hipStream_t stream) {
  (void)in_sizes; (void)n_in; (void)out_size; (void)ws_size;
  const float* x1 = (const float*)d_in[0];
  const int* v1 = (const int*)d_in[1];
  const int* e1 = (const int*)d_in[2];
  const float* x2 = (const float*)d_in[3];
  const int* v2 = (const int*)d_in[4];
  const int* e2 = (const int*)d_in[5];
  const float* lin_w = (const float*)d_in[6];
  const float* lin_b = (const float*)d_in[7];
  const float* w1g = (const float*)d_in[8];
  const float* w1bn = (const float*)d_in[9];
  const float* w1w = (const float*)d_in[10];
  const float* w1b = (const float*)d_in[11];
  const float* w2g = (const float*)d_in[12];
  const float* w2bn = (const float*)d_in[13];
  const float* w2w = (const float*)d_in[14];
  const float* w2b = (const float*)d_in[15];
  const float* wg = (const float*)d_in[16];
  const float* wbn = (const float*)d_in[17];
  const float* ww = (const float*)d_in[18];
  const float* wb = (const float*)d_in[19];
  const float* cw1 = (const float*)d_in[20];
  const float* cb1 = (const float*)d_in[21];
  const float* cg = (const float*)d_in[22];
  const float* cbn = (const float*)d_in[23];
  const float* cw2 = (const float*)d_in[24];
  const float* cb2 = (const float*)d_in[25];

  char* p = (char*)d_ws;
  auto alloc = [&](size_t bytes) {
    char* r = p;
    p += (bytes + 255) & ~(size_t)255;
    return r;
  };
  float* X = (float*)alloc((size_t)NN * 128 * 4);
  float* X0 = (float*)alloc((size_t)NN * 128 * 4);
  float* B = (float*)alloc((size_t)NN * 128 * 4);
  float* Qb = (float*)alloc((size_t)NN * 128 * 4);
  float* Xe = (float*)alloc((size_t)NH * 128 * 4);
  float* sn = (float*)alloc((size_t)NN * 4);
  float* qn = (float*)alloc((size_t)NN * 4);
  float* se = (float*)alloc((size_t)NH * 4);
  float* qe = (float*)alloc((size_t)NH * 4);
  float* suma = (float*)alloc((size_t)NN * 4);
  float* invdeg = (float*)alloc((size_t)NN * 4);
  float* t2arr = (float*)alloc((size_t)NN * 4);
  int* starts_e_all = (int*)alloc((size_t)2 * (NH + 1) * 4);
  int* starts_v_all = (int*)alloc((size_t)2 * (NN + 1) * 4);
  int* cursor_all = (int*)alloc((size_t)2 * NH * 4);
  int* bsums_all = (int*)alloc((size_t)2 * 1024 * 4);
  int* v_by_e1 = (int*)alloc((size_t)NI * 4);
  int* v_by_e2 = (int*)alloc((size_t)NI * 4);
  int* e_by_v1 = (int*)alloc((size_t)NI * 4);
  int* e_by_v2 = (int*)alloc((size_t)NI * 4);
  float* W2g = (float*)alloc((size_t)256 * 128 * 4);
  float* s_g = (float*)alloc(128 * 4);
  float* c0 = (float*)alloc(128 * 4);

  int* se1 = starts_e_all;
  int* se2 = starts_e_all + (NH + 1);
  int* sv1 = starts_v_all;
  int* sv2 = starts_v_all + (NN + 1);
  int* cur1 = cursor_all;
  int* cur2 = cursor_all + NH;
  int* bs1 = bsums_all;
  int* bs2 = bsums_all + 1024;

  // W2 precompute (shared by both branches)
  k_prep_w2g<<<128, 256, 0, stream>>>(w2w, w2g, W2g);
  k_prep_sgc0<<<1, 128, 0, stream>>>(w2w, w2g, w2bn, w2b, s_g, c0);

  const int GBI = (NI + 255) / 256;
  const int GBE = (NH + 1023) / 1024;
  const int GBV = (NN + 1023) / 1024;
  const int GHE = (NH + 255) / 256;
  const int GHV = (NN + 255) / 256;

  // ---- CSR by hedge, both branches ----
  hipMemsetAsync(starts_e_all, 0, (size_t)2 * (NH + 1) * 4, stream);
  k_hist2<<<2 * GBI, 256, 0, stream>>>(e1, e2, NI, se1, se2);
  k_scan1_2<<<2 * GBE, 1024, 0, stream>>>(se1, se2, NH, bs1, bs2);
  k_scan2_2<<<2, 1024, 0, stream>>>(bs1, bs2, GBE);
  k_scan3_2<<<2 * GHE, 256, 0, stream>>>(se1, se2, bs1, bs2, NH, NI);
  hipMemsetAsync(cursor_all, 0, (size_t)2 * NH * 4, stream);
  k_fill2<<<2 * GBI, 256, 0, stream>>>(e1, v1, e2, v2, NI, se1, se2, cur1, cur2,
                                       v_by_e1, v_by_e2);
  k_sort2<<<2 * GHE, 256, 0, stream>>>(se1, se2, NH, v_by_e1, v_by_e2);
  // ---- CSR by node, both branches ----
  hipMemsetAsync(starts_v_all, 0, (size_t)2 * (NN + 1) * 4, stream);
  k_hist2<<<2 * GBI, 256, 0, stream>>>(v1, v2, NI, sv1, sv2);
  k_scan1_2<<<2 * GBV, 1024, 0, stream>>>(sv1, sv2, NN, bs1, bs2);
  k_scan2_2<<<2, 1024, 0, stream>>>(bs1, bs2, GBV);
  k_scan3_2<<<2 * GHV, 256, 0, stream>>>(sv1, sv2, bs1, bs2, NN, NI);
  hipMemsetAsync(cursor_all, 0, (size_t)2 * NH * 4, stream);
  k_fill2<<<2 * GBI, 256, 0, stream>>>(v1, e1, v2, e2, NI, sv1, sv2, cur1, cur2,
                                       e_by_v1, e_by_v2);
  k_sort2<<<2 * GHV, 256, 0, stream>>>(sv1, sv2, NN, e_by_v1, e_by_v2);

  float* out = (float*)d_out;
  run_branch(x1, lin_w, lin_b, w1g, w1bn, w1w, w1b, W2g, s_g, c0,
             wg, wbn, ww, wb, cw1, cb1, cg, cbn, cw2, cb2,
             X, X0, B, Qb, Xe, sn, qn, se, qe, suma, invdeg, t2arr,
             se1, sv1, v_by_e1, e_by_v1, out, stream);
  run_branch(x2, lin_w, lin_b, w1g, w1bn, w1w, w1b, W2g, s_g, c0,
             wg, wbn, ww, wb, cw1, cb1, cg, cbn, cw2, cb2,
             X, X0, B, Qb, Xe, sn, qn, se, qe, suma, invdeg, t2arr,
             se2, sv2, v_by_e2, e_by_v2, out + NN, stream);
}

// Round 17
// 1644.157 us; speedup vs baseline: 1.3294x; 1.3294x over previous
//
#include <hip/hip_runtime.h>

#define NN 50000
#define NH 100000
#define NI 600000
#define FIN 512
#define HID 128
#define LNEPS 1e-5f

static __device__ __forceinline__ void fma4(float4& a, float s, const float4& w) {
  a.x += s * w.x; a.y += s * w.y; a.z += s * w.z; a.w += s * w.w;
}
static __device__ __forceinline__ float f4c(const float4& a, int k) {
  return k == 0 ? a.x : k == 1 ? a.y : k == 2 ? a.z : a.w;
}

// ============================ CSR build (both branches per launch) ============================
__global__ void k_hist2(const int* __restrict__ i1, const int* __restrict__ i2, int n,
                        int* __restrict__ d1, int* __restrict__ d2) {
  int nb = gridDim.x >> 1, blk = blockIdx.x;
  bool a = blk < nb;
  const int* idx = a ? i1 : i2;
  int* deg = a ? d1 : d2;
  int i = (a ? blk : blk - nb) * 256 + threadIdx.x;
  if (i < n) atomicAdd(&deg[idx[i]], 1);
}

__global__ __launch_bounds__(1024) void k_scan1_2(int* __restrict__ dd1, int* __restrict__ dd2,
                                                  int m, int* __restrict__ b1,
                                                  int* __restrict__ b2) {
  __shared__ int sh[1024];
  int nb = gridDim.x >> 1, blk = blockIdx.x;
  bool a = blk < nb;
  int* data = a ? dd1 : dd2;
  int* bsums = a ? b1 : b2;
  int lb = a ? blk : blk - nb;
  int tid = threadIdx.x;
  int i = lb * 1024 + tid;
  int v = (i < m) ? data[i] : 0;
  sh[tid] = v;
  __syncthreads();
  for (int off = 1; off < 1024; off <<= 1) {
    int tv = (tid >= off) ? sh[tid - off] : 0;
    __syncthreads();
    sh[tid] += tv;
    __syncthreads();
  }
  if (i < m) data[i] = sh[tid] - v;  // exclusive
  if (tid == 1023) bsums[lb] = sh[1023];
}

__global__ __launch_bounds__(1024) void k_scan2_2(int* __restrict__ b1, int* __restrict__ b2,
                                                  int nb) {
  __shared__ int sh[1024];
  int* bsums = blockIdx.x == 0 ? b1 : b2;
  int tid = threadIdx.x;
  int v = (tid < nb) ? bsums[tid] : 0;
  sh[tid] = v;
  __syncthreads();
  for (int off = 1; off < 1024; off <<= 1) {
    int tv = (tid >= off) ? sh[tid - off] : 0;
    __syncthreads();
    sh[tid] += tv;
    __syncthreads();
  }
  if (tid < nb) bsums[tid] = sh[tid] - v;
}

__global__ void k_scan3_2(int* __restrict__ dd1, int* __restrict__ dd2,
                          const int* __restrict__ b1, const int* __restrict__ b2,
                          int m, int total) {
  int nb = gridDim.x >> 1, blk = blockIdx.x;
  bool a = blk < nb;
  int* data = a ? dd1 : dd2;
  const int* bs = a ? b1 : b2;
  int i = (a ? blk : blk - nb) * 256 + threadIdx.x;
  if (i < m) data[i] += bs[i >> 10];
  if (i == 0) data[m] = total;
}

__global__ void k_fill2(const int* __restrict__ k1, const int* __restrict__ o1,
                        const int* __restrict__ k2, const int* __restrict__ o2, int n,
                        const int* __restrict__ s1, const int* __restrict__ s2,
                        int* __restrict__ c1, int* __restrict__ c2,
                        int* __restrict__ out1, int* __restrict__ out2) {
  int nb = gridDim.x >> 1, blk = blockIdx.x;
  bool a = blk < nb;
  const int* key = a ? k1 : k2;
  const int* oth = a ? o1 : o2;
  const int* st = a ? s1 : s2;
  int* cur = a ? c1 : c2;
  int* out = a ? out1 : out2;
  int i = (a ? blk : blk - nb) * 256 + threadIdx.x;
  if (i >= n) return;
  int k = key[i];
  int pos = st[k] + atomicAdd(&cur[k], 1);
  out[pos] = oth[i];
}

// Sort each CSR segment ascending -> deterministic order every replay.
__global__ void k_sort2(const int* __restrict__ s1, const int* __restrict__ s2, int nseg,
                        int* __restrict__ v1, int* __restrict__ v2) {
  int nb = gridDim.x >> 1, blk = blockIdx.x;
  bool a = blk < nb;
  const int* starts = a ? s1 : s2;
  int* vals = a ? v1 : v2;
  int seg = (a ? blk : blk - nb) * 256 + threadIdx.x;
  if (seg >= nseg) return;
  int s = starts[seg], e = starts[seg + 1];
  int d = e - s;
  if (d <= 1) return;
  if (d <= 48) {
    int buf[48];
    for (int i = 0; i < d; i++) buf[i] = vals[s + i];
    for (int i = 1; i < d; i++) {
      int key = buf[i], j = i - 1;
      while (j >= 0 && buf[j] > key) { buf[j + 1] = buf[j]; j--; }
      buf[j + 1] = key;
    }
    for (int i = 0; i < d; i++) vals[s + i] = buf[i];
  } else {
    for (int i = s + 1; i < e; i++) {
      int key = vals[i], j = i - 1;
      while (j >= s && vals[j] > key) { vals[j + 1] = vals[j]; j--; }
      vals[j + 1] = key;
    }
  }
}

// ============================ W2 precompute ============================
__global__ void k_prep_w2g(const float* __restrict__ W2, const float* __restrict__ g2,
                           float* __restrict__ W2g) {
  int i = blockIdx.x * 256 + threadIdx.x;
  if (i >= 256 * 128) return;
  int k = i >> 7;
  W2g[i] = g2[k] * W2[i];
}

__global__ __launch_bounds__(128) void k_prep_sgc0(
    const float* __restrict__ W2, const float* __restrict__ g2,
    const float* __restrict__ b2, const float* __restrict__ bias2,
    float* __restrict__ s_g, float* __restrict__ c0) {
  int t = threadIdx.x;
  float sg = 0.f, cc = 0.f;
  for (int k = 0; k < 256; k++) {
    float w = W2[k * 128 + t];
    sg += g2[k] * w;
    cc += b2[k] * w;
  }
  s_g[t] = sg;
  c0[t] = cc + bias2[t];
}

// ============================ GEMM primitives ============================
// Ash: 32x128 A tile (stride 132). Wsh16 = 16 k-rows x 128 cols (aliased in [32][68]).
// Thread (tc=t&15, tr=t>>4): rows tr*2..+1, cols {tc*4..+3, 64+tc*4..+3}; 2-way bank (free).
static __device__ __forceinline__ void stage_w16(float (*Wsh)[132], const float* __restrict__ W,
                                                 int row0, int t) {
  for (int s = t; s < 512; s += 256) {
    int k = s >> 5, c4 = (s & 31) * 4;
    *(float4*)&Wsh[k][c4] = *(const float4*)(W + (size_t)(row0 + k) * 128 + c4);
  }
}

static __device__ __forceinline__ void gemm128(const float (*Ash)[132], float (*Wsh)[132],
                                               const float* __restrict__ W,
                                               int t, int tc, int tr,
                                               float4 acc0[2], float4 acc1[2]) {
  for (int kk = 0; kk < 8; kk++) {
    __syncthreads();  // prior Wsh readers / Ash writers done
    stage_w16(Wsh, W, kk * 16, t);
    __syncthreads();
    const int kb = kk * 16;
#pragma unroll
    for (int k4 = 0; k4 < 16; k4 += 4) {
      float4 a0 = *(const float4*)&Ash[tr * 2 + 0][kb + k4];
      float4 a1 = *(const float4*)&Ash[tr * 2 + 1][kb + k4];
#pragma unroll
      for (int kk2 = 0; kk2 < 4; kk2++) {
        float4 w0 = *(const float4*)&Wsh[k4 + kk2][tc * 4];
        float4 w1 = *(const float4*)&Wsh[k4 + kk2][64 + tc * 4];
        float a0v = f4c(a0, kk2), a1v = f4c(a1, kk2);
        fma4(acc0[0], a0v, w0); fma4(acc0[1], a0v, w1);
        fma4(acc1[0], a1v, w0); fma4(acc1[1], a1v, w1);
      }
    }
  }
}

// Legacy 64-col-half core (kept for the 64-col classifier GEMM).
static __device__ __forceinline__ void stage_w(float (*Wsh)[68], const float* __restrict__ W,
                                               int ldw, int row0, int col0, int t) {
  for (int s = t; s < 512; s += 256) {
    int k = s >> 4, c4 = (s & 15) * 4;
    *(float4*)&Wsh[k][c4] = *(const float4*)(W + (size_t)(row0 + k) * ldw + col0 + c4);
  }
}

static __device__ __forceinline__ void inner32(const float (*Ash)[132], const float (*Wsh)[68],
                                               int kb, int tc, int tr,
                                               float4& acc0, float4& acc1) {
#pragma unroll
  for (int k = 0; k < 32; k += 4) {
    float4 w0 = *(const float4*)&Wsh[k + 0][tc * 4];
    float4 w1 = *(const float4*)&Wsh[k + 1][tc * 4];
    float4 w2 = *(const float4*)&Wsh[k + 2][tc * 4];
    float4 w3 = *(const float4*)&Wsh[k + 3][tc * 4];
    float4 a0 = *(const float4*)&Ash[tr * 2 + 0][kb + k];
    float4 a1 = *(const float4*)&Ash[tr * 2 + 1][kb + k];
    fma4(acc0, a0.x, w0); fma4(acc0, a0.y, w1); fma4(acc0, a0.z, w2); fma4(acc0, a0.w, w3);
    fma4(acc1, a1.x, w0); fma4(acc1, a1.y, w1); fma4(acc1, a1.z, w2); fma4(acc1, a1.w, w3);
  }
}

static __device__ __forceinline__ void load_a128(float (*Ash)[132], const float* __restrict__ A,
                                                 int r0, int N, int t) {
  for (int s = t; s < 1024; s += 256) {
    int r = s >> 5, c4 = (s & 31) * 4;
    float4 val = {0, 0, 0, 0};
    if (r0 + r < N) val = *(const float4*)(A + (size_t)(r0 + r) * 128 + c4);
    *(float4*)&Ash[r][c4] = val;
  }
}

// Load A tile scaled per-row: Ash[r][:] = scale[r0+r] * A[r0+r][:]
static __device__ __forceinline__ void load_a128s(float (*Ash)[132], const float* __restrict__ A,
                                                  const float* __restrict__ scale,
                                                  int r0, int N, int t) {
  for (int s = t; s < 1024; s += 256) {
    int r = s >> 5, c4 = (s & 31) * 4;
    float4 val = {0, 0, 0, 0};
    if (r0 + r < N) {
      float sc = scale[r0 + r];
      float4 x = *(const float4*)(A + (size_t)(r0 + r) * 128 + c4);
      val.x = sc * x.x; val.y = sc * x.y; val.z = sc * x.z; val.w = sc * x.w;
    }
    *(float4*)&Ash[r][c4] = val;
  }
}

// LN rows of Ash in place (stats optional), 4 waves x 8 rows (wave-local rows).
template <bool STATS>
static __device__ __forceinline__ void ln_tile(float (*Ash)[132], const float* __restrict__ g,
                                               const float* __restrict__ b,
                                               float* __restrict__ sn, float* __restrict__ qn,
                                               int r0, int N, int t) {
  int wv = t >> 6, lane = t & 63;
  for (int j = 0; j < 8; j++) {
    int r = wv * 8 + j;
    if (r0 + r < N) {
      float2 x = *(float2*)&Ash[r][lane * 2];
      float s = x.x + x.y, sq = x.x * x.x + x.y * x.y;
      for (int m = 1; m < 64; m <<= 1) { s += __shfl_xor(s, m); sq += __shfl_xor(sq, m); }
      if (STATS && lane == 0) { sn[r0 + r] = s; qn[r0 + r] = sq; }
      float mu = s * (1.f / 128.f);
      float var = sq * (1.f / 128.f) - mu * mu;
      float rstd = rsqrtf(var + LNEPS);
      float2 gg = ((const float2*)g)[lane];
      float2 bb = ((const float2*)b)[lane];
      float2 o;
      o.x = (x.x - mu) * rstd * gg.x + bb.x;
      o.y = (x.y - mu) * rstd * gg.y + bb.y;
      *(float2*)&Ash[r][lane * 2] = o;
    }
  }
}

// ============================ proj + relu + LN-stats + W1 GEMM ============================
__global__ __launch_bounds__(256) void k_proj_fused(
    const float* __restrict__ x_in, const float* __restrict__ lin_w,
    const float* __restrict__ lin_b, const float* __restrict__ w1g,
    const float* __restrict__ w1bn, const float* __restrict__ w1w,
    const float* __restrict__ w1b, float* __restrict__ X0,
    float* __restrict__ B, float* __restrict__ sn, float* __restrict__ qn, int N) {
  __shared__ float Ash[32][132];
  __shared__ float Wsh[32][68];
  float (*W16)[132] = (float(*)[132])Wsh;
  const int t = threadIdx.x;
  const int r0 = blockIdx.x * 32;
  const int tc = t & 15, tr = t >> 4;
  float4 acc0[2] = {{0,0,0,0},{0,0,0,0}}, acc1[2] = {{0,0,0,0},{0,0,0,0}};
  for (int kq = 0; kq < 4; kq++) {
    __syncthreads();
    for (int s = t; s < 1024; s += 256) {
      int r = s >> 5, c4 = (s & 31) * 4;
      float4 val = {0, 0, 0, 0};
      if (r0 + r < N) val = *(const float4*)(x_in + (size_t)(r0 + r) * 512 + kq * 128 + c4);
      *(float4*)&Ash[r][c4] = val;
    }
    gemm128((const float(*)[132])Ash, W16, lin_w + (size_t)kq * 128 * 128, t, tc, tr,
            acc0, acc1);
  }
  __syncthreads();
  for (int h = 0; h < 2; h++) {
    int c = h * 64 + tc * 4;
    float4 bb = *(const float4*)(lin_b + c);
    int row0 = r0 + tr * 2;
    float4 z0, z1;
    z0.x = fmaxf(acc0[h].x + bb.x, 0.f); z0.y = fmaxf(acc0[h].y + bb.y, 0.f);
    z0.z = fmaxf(acc0[h].z + bb.z, 0.f); z0.w = fmaxf(acc0[h].w + bb.w, 0.f);
    z1.x = fmaxf(acc1[h].x + bb.x, 0.f); z1.y = fmaxf(acc1[h].y + bb.y, 0.f);
    z1.z = fmaxf(acc1[h].z + bb.z, 0.f); z1.w = fmaxf(acc1[h].w + bb.w, 0.f);
    if (row0 < N) {
      *(float4*)(X0 + (size_t)row0 * 128 + c) = z0;
      *(float4*)&Ash[tr * 2][c] = z0;
    }
    if (row0 + 1 < N) {
      *(float4*)(X0 + (size_t)(row0 + 1) * 128 + c) = z1;
      *(float4*)&Ash[tr * 2 + 1][c] = z1;
    }
  }
  __syncthreads();
  ln_tile<true>(Ash, w1g, w1bn, sn, qn, r0, N, t);
  float4 f0[2] = {{0,0,0,0},{0,0,0,0}}, f1[2] = {{0,0,0,0},{0,0,0,0}};
  gemm128((const float(*)[132])Ash, W16, w1w, t, tc, tr, f0, f1);
  for (int h = 0; h < 2; h++) {
    int c = h * 64 + tc * 4;
    float4 bb = *(const float4*)(w1b + c);
    int row0 = r0 + tr * 2;
    if (row0 < N) {
      float4 o = {f0[h].x + bb.x, f0[h].y + bb.y, f0[h].z + bb.z, f0[h].w + bb.w};
      *(float4*)(B + (size_t)row0 * 128 + c) = o;
    }
    if (row0 + 1 < N) {
      float4 o = {f1[h].x + bb.x, f1[h].y + bb.y, f1[h].z + bb.z, f1[h].w + bb.w};
      *(float4*)(B + (size_t)(row0 + 1) * 128 + c) = o;
    }
  }
}

// ============================ hedge mean gather (half-wave per hedge) ============================
__global__ __launch_bounds__(256) void k_xe(
    const float* __restrict__ B, const int* __restrict__ starts,
    const int* __restrict__ vlist, float* __restrict__ Xe,
    float* __restrict__ se, float* __restrict__ qe, int M) {
  int half = threadIdx.x >> 5, lane = threadIdx.x & 31;
  int m = blockIdx.x * 8 + half;
  if (m >= M) return;
  int s = starts[m], e = starts[m + 1];
  float4 acc = {0.f, 0.f, 0.f, 0.f};
  for (int j = s; j < e; j++) {
    int vv = vlist[j];
    float4 val = ((const float4*)(B + (size_t)vv * 128))[lane];
    acc.x += val.x; acc.y += val.y; acc.z += val.z; acc.w += val.w;
  }
  int d = e - s;
  float inv = d > 0 ? 1.f / (float)d : 0.f;
  float4 o = {acc.x * inv, acc.y * inv, acc.z * inv, acc.w * inv};
  ((float4*)(Xe + (size_t)m * 128))[lane] = o;
  float ss = o.x + o.y + o.z + o.w;
  float qq = o.x * o.x + o.y * o.y + o.z * o.z + o.w * o.w;
  for (int mm = 1; mm < 32; mm <<= 1) {
    ss += __shfl_xor(ss, mm, 32);
    qq += __shfl_xor(qq, mm, 32);
  }
  if (lane == 0) { se[m] = ss; qe[m] = qq; }
}

// ============================ node gather (half-wave per node) ============================
__global__ __launch_bounds__(256) void k_nodeg(
    const float* __restrict__ Xe, const int* __restrict__ starts_v,
    const int* __restrict__ e_by_v, const float* __restrict__ sn,
    const float* __restrict__ qn, const float* __restrict__ se,
    const float* __restrict__ qe, float* __restrict__ Qb,
    float* __restrict__ suma_arr, float* __restrict__ invdeg,
    float* __restrict__ t2arr, int N) {
  int half = threadIdx.x >> 5, lane = threadIdx.x & 31;
  int v = blockIdx.x * 8 + half;
  if (v >= N) return;
  int s = starts_v[v], e = starts_v[v + 1];
  float svn = sn[v], qvn = qn[v];
  float4 acc = {0.f, 0.f, 0.f, 0.f};
  float suma = 0.f, sumb = 0.f;
  for (int j = s; j < e; j++) {
    int ee = e_by_v[j];
    float mu = (svn + se[ee]) * (1.f / 256.f);
    float e2 = (qvn + qe[ee]) * (1.f / 256.f);
    float rstd = rsqrtf(e2 - mu * mu + LNEPS);
    suma += rstd;
    sumb += mu * rstd;
    float4 vv = ((const float4*)(Xe + (size_t)ee * 128))[lane];
    acc.x += rstd * vv.x; acc.y += rstd * vv.y;
    acc.z += rstd * vv.z; acc.w += rstd * vv.w;
  }
  ((float4*)(Qb + (size_t)v * 128))[lane] = acc;
  if (lane == 0) {
    int d = e - s;
    float inv = d > 0 ? 1.f / (float)d : 0.f;
    suma_arr[v] = suma;
    invdeg[v] = inv;
    t2arr[v] = sumb * inv;
  }
}

// ======== shared conv2 body: [suma*X | Qb]@W2g + epilogue(blend) + LN(wg,wbn) into Ash ========
static __device__ __forceinline__ void conv2_body(
    float (*Ash)[132], float (*Wsh)[132],
    const float* __restrict__ Xsrc, const float* __restrict__ suma,
    const float* __restrict__ Q, const float* __restrict__ W,
    const float* __restrict__ invdeg, const float* __restrict__ t2arr,
    const float* __restrict__ s_g, const float* __restrict__ c0,
    const float* __restrict__ X0, const float* __restrict__ wg,
    const float* __restrict__ wbn, int r0, int N, int t, int tc, int tr) {
  float4 acc0[2] = {{0,0,0,0},{0,0,0,0}}, acc1[2] = {{0,0,0,0},{0,0,0,0}};
  for (int ph = 0; ph < 2; ph++) {
    __syncthreads();
    if (ph == 0) load_a128s(Ash, Xsrc, suma, r0, N, t);
    else load_a128(Ash, Q, r0, N, t);
    gemm128((const float(*)[132])Ash, Wsh, W + (size_t)ph * 128 * 128, t, tc, tr,
            acc0, acc1);
  }
  __syncthreads();
  for (int r = 0; r < 2; r++) {
    int row = r0 + tr * 2 + r;
    if (row < N) {
      float t1 = invdeg[row], t2 = t2arr[row];
      float flag = t1 > 0.f ? 1.f : 0.f;
      for (int h = 0; h < 2; h++) {
        int c = h * 64 + tc * 4;
        float4 g = r ? acc1[h] : acc0[h];
        float4 sg = *(const float4*)(s_g + c);
        float4 cc = *(const float4*)(c0 + c);
        float4 x0 = *(const float4*)(X0 + (size_t)row * 128 + c);
        float4 z;
        z.x = 0.5f * (g.x * t1 - t2 * sg.x + flag * cc.x) + 0.5f * x0.x;
        z.y = 0.5f * (g.y * t1 - t2 * sg.y + flag * cc.y) + 0.5f * x0.y;
        z.z = 0.5f * (g.z * t1 - t2 * sg.z + flag * cc.z) + 0.5f * x0.z;
        z.w = 0.5f * (g.w * t1 - t2 * sg.w + flag * cc.w) + 0.5f * x0.w;
        *(float4*)&Ash[tr * 2 + r][c] = z;
      }
    }
  }
  __syncthreads();
  ln_tile<false>(Ash, wg, wbn, nullptr, nullptr, r0, N, t);
}

// ============ conv2 + W-GEMM+relu -> X ; LN-stats ; W1 GEMM -> B (layer 0) ============
__global__ __launch_bounds__(256) void k_conv2w(
    const float* __restrict__ Xsrc, const float* __restrict__ suma,
    const float* __restrict__ Q, const float* __restrict__ W,
    const float* __restrict__ invdeg, const float* __restrict__ t2arr,
    const float* __restrict__ s_g, const float* __restrict__ c0,
    const float* __restrict__ X0, const float* __restrict__ wg,
    const float* __restrict__ wbn, const float* __restrict__ Ww,
    const float* __restrict__ wb, const float* __restrict__ w1g,
    const float* __restrict__ w1bn, const float* __restrict__ w1w,
    const float* __restrict__ w1b, float* __restrict__ Xout,
    float* __restrict__ B, float* __restrict__ sn, float* __restrict__ qn, int N) {
  __shared__ float Ash[32][132];
  __shared__ float Wsh[32][68];
  float (*W16)[132] = (float(*)[132])Wsh;
  const int t = threadIdx.x;
  const int r0 = blockIdx.x * 32;
  const int tc = t & 15, tr = t >> 4;
  conv2_body(Ash, W16, Xsrc, suma, Q, W, invdeg, t2arr, s_g, c0, X0, wg, wbn,
             r0, N, t, tc, tr);
  float4 b0[2] = {{0,0,0,0},{0,0,0,0}}, b1[2] = {{0,0,0,0},{0,0,0,0}};
  gemm128((const float(*)[132])Ash, W16, Ww, t, tc, tr, b0, b1);
  __syncthreads();
  for (int h = 0; h < 2; h++) {
    int c = h * 64 + tc * 4;
    float4 bb = *(const float4*)(wb + c);
    int row0 = r0 + tr * 2;
    float4 z0, z1;
    z0.x = fmaxf(b0[h].x + bb.x, 0.f); z0.y = fmaxf(b0[h].y + bb.y, 0.f);
    z0.z = fmaxf(b0[h].z + bb.z, 0.f); z0.w = fmaxf(b0[h].w + bb.w, 0.f);
    z1.x = fmaxf(b1[h].x + bb.x, 0.f); z1.y = fmaxf(b1[h].y + bb.y, 0.f);
    z1.z = fmaxf(b1[h].z + bb.z, 0.f); z1.w = fmaxf(b1[h].w + bb.w, 0.f);
    if (row0 < N) {
      *(float4*)(Xout + (size_t)row0 * 128 + c) = z0;
      *(float4*)&Ash[tr * 2][c] = z0;
    }
    if (row0 + 1 < N) {
      *(float4*)(Xout + (size_t)(row0 + 1) * 128 + c) = z1;
      *(float4*)&Ash[tr * 2 + 1][c] = z1;
    }
  }
  __syncthreads();
  ln_tile<true>(Ash, w1g, w1bn, sn, qn, r0, N, t);
  float4 f0[2] = {{0,0,0,0},{0,0,0,0}}, f1[2] = {{0,0,0,0},{0,0,0,0}};
  gemm128((const float(*)[132])Ash, W16, w1w, t, tc, tr, f0, f1);
  for (int h = 0; h < 2; h++) {
    int c = h * 64 + tc * 4;
    float4 bb = *(const float4*)(w1b + c);
    int row0 = r0 + tr * 2;
    if (row0 < N) {
      float4 o = {f0[h].x + bb.x, f0[h].y + bb.y, f0[h].z + bb.z, f0[h].w + bb.w};
      *(float4*)(B + (size_t)row0 * 128 + c) = o;
    }
    if (row0 + 1 < N) {
      float4 o = {f1[h].x + bb.x, f1[h].y + bb.y, f1[h].z + bb.z, f1[h].w + bb.w};
      *(float4*)(B + (size_t)(row0 + 1) * 128 + c) = o;
    }
  }
}

// ============ conv2 + W-GEMM+relu ; classifier (cw1 GEMM, LN64, dot) (layer 1) ============
__global__ __launch_bounds__(256) void k_conv2c(
    const float* __restrict__ Xsrc, const float* __restrict__ suma,
    const float* __restrict__ Q, const float* __restrict__ W,
    const float* __restrict__ invdeg, const float* __restrict__ t2arr,
    const float* __restrict__ s_g, const float* __restrict__ c0,
    const float* __restrict__ X0, const float* __restrict__ wg,
    const float* __restrict__ wbn, const float* __restrict__ Ww,
    const float* __restrict__ wb, const float* __restrict__ cw1,
    const float* __restrict__ cb1, const float* __restrict__ cg,
    const float* __restrict__ cbn, const float* __restrict__ cw2,
    const float* __restrict__ cb2, float* __restrict__ out, int N) {
  __shared__ float Ash[32][132];
  __shared__ float Wsh[32][68];
  float (*W16)[132] = (float(*)[132])Wsh;
  const int t = threadIdx.x;
  const int r0 = blockIdx.x * 32;
  const int tc = t & 15, tr = t >> 4;
  conv2_body(Ash, W16, Xsrc, suma, Q, W, invdeg, t2arr, s_g, c0, X0, wg, wbn,
             r0, N, t, tc, tr);
  float4 b0[2] = {{0,0,0,0},{0,0,0,0}}, b1[2] = {{0,0,0,0},{0,0,0,0}};
  gemm128((const float(*)[132])Ash, W16, Ww, t, tc, tr, b0, b1);
  __syncthreads();
  for (int h = 0; h < 2; h++) {
    int c = h * 64 + tc * 4;
    float4 bb = *(const float4*)(wb + c);
    int row0 = r0 + tr * 2;
    if (row0 < N) {
      float4 z;
      z.x = fmaxf(b0[h].x + bb.x, 0.f); z.y = fmaxf(b0[h].y + bb.y, 0.f);
      z.z = fmaxf(b0[h].z + bb.z, 0.f); z.w = fmaxf(b0[h].w + bb.w, 0.f);
      *(float4*)&Ash[tr * 2][c] = z;
    }
    if (row0 + 1 < N) {
      float4 z;
      z.x = fmaxf(b1[h].x + bb.x, 0.f); z.y = fmaxf(b1[h].y + bb.y, 0.f);
      z.z = fmaxf(b1[h].z + bb.z, 0.f); z.w = fmaxf(b1[h].w + bb.w, 0.f);
      *(float4*)&Ash[tr * 2 + 1][c] = z;
    }
  }
  // H = relu(Z @ cw1 + cb1): 64 cols (legacy core)
  float4 h0 = {0,0,0,0}, h1 = {0,0,0,0};
  for (int kc = 0; kc < 4; kc++) {
    __syncthreads();
    stage_w(Wsh, cw1, 64, kc * 32, 0, t);
    __syncthreads();
    inner32((const float(*)[132])Ash, (const float(*)[68])Wsh, kc * 32, tc, tr, h0, h1);
  }
  __syncthreads();
  {
    int c = tc * 4;
    float4 bb = *(const float4*)(cb1 + c);
    float4 z;
    z.x = fmaxf(h0.x + bb.x, 0.f); z.y = fmaxf(h0.y + bb.y, 0.f);
    z.z = fmaxf(h0.z + bb.z, 0.f); z.w = fmaxf(h0.w + bb.w, 0.f);
    *(float4*)&Wsh[tr * 2][c] = z;
    z.x = fmaxf(h1.x + bb.x, 0.f); z.y = fmaxf(h1.y + bb.y, 0.f);
    z.z = fmaxf(h1.z + bb.z, 0.f); z.w = fmaxf(h1.w + bb.w, 0.f);
    *(float4*)&Wsh[tr * 2 + 1][c] = z;
  }
  __syncthreads();
  int wv = t >> 6, lane = t & 63;
  for (int j = 0; j < 8; j++) {
    int r = wv * 8 + j;
    if (r0 + r < N) {
      float h = Wsh[r][lane];
      float s = h, sq = h * h;
      for (int m = 1; m < 64; m <<= 1) { s += __shfl_xor(s, m); sq += __shfl_xor(sq, m); }
      float mu = s * (1.f / 64.f);
      float var = sq * (1.f / 64.f) - mu * mu;
      float rstd = rsqrtf(var + LNEPS);
      float hn = (h - mu) * rstd * cg[lane] + cbn[lane];
      float c = hn * cw2[lane];
      for (int m = 1; m < 64; m <<= 1) c += __shfl_xor(c, m);
      if (lane == 0) out[r0 + r] = c + cb2[0];
    }
  }
}

// ============================ per-branch pipeline (CSR prebuilt) ============================
static void run_branch(const float* x_in,
                       const float* lin_w, const float* lin_b,
                       const float* w1g, const float* w1bn, const float* w1w, const float* w1b,
                       const float* W2g, const float* s_g, const float* c0,
                       const float* wg, const float* wbn, const float* ww, const float* wb,
                       const float* cw1, const float* cb1, const float* cg, const float* cbn,
                       const float* cw2, const float* cb2,
                       float* X, float* X0, float* B, float* Qb, float* Xe,
                       float* sn, float* qn, float* se, float* qe,
                       float* suma, float* invdeg, float* t2arr,
                       const int* starts_e, const int* starts_v,
                       const int* v_by_e, const int* e_by_v,
                       float* out, hipStream_t stream) {
  const int GN = (NN + 31) / 32;
  k_proj_fused<<<GN, 256, 0, stream>>>(x_in, lin_w, lin_b, w1g, w1bn, w1w, w1b,
                                       X0, B, sn, qn, NN);
  for (int layer = 0; layer < 2; ++layer) {
    const float* Xsrc = layer == 0 ? X0 : X;
    k_xe<<<NH / 8, 256, 0, stream>>>(B, starts_e, v_by_e, Xe, se, qe, NH);
    k_nodeg<<<(NN + 7) / 8, 256, 0, stream>>>(Xe, starts_v, e_by_v, sn, qn, se, qe,
                                              Qb, suma, invdeg, t2arr, NN);
    if (layer == 0) {
      k_conv2w<<<GN, 256, 0, stream>>>(Xsrc, suma, Qb, W2g, invdeg, t2arr, s_g, c0,
                                       X0, wg, wbn, ww, wb, w1g, w1bn, w1w, w1b,
                                       X, B, sn, qn, NN);
    } else {
      k_conv2c<<<GN, 256, 0, stream>>>(Xsrc, suma, Qb, W2g, invdeg, t2arr, s_g, c0,
                                       X0, wg, wbn, ww, wb, cw1, cb1, cg, cbn,
                                       cw2, cb2, out, NN);
    }
  }
}

extern "C" void kernel_launch(void* const* d_in, const int* in_sizes, int n_in,
                              void* d_out, int out_size, void* d_ws, size_t ws_size,
                              hipStream_t stream) {
  (void)in_sizes; (void)n_in; (void)out_size; (void)ws_size;
  const float* x1 = (const float*)d_in[0];
  const int* v1 = (const int*)d_in[1];
  const int* e1 = (const int*)d_in[2];
  const float* x2 = (const float*)d_in[3];
  const int* v2 = (const int*)d_in[4];
  const int* e2 = (const int*)d_in[5];
  const float* lin_w = (const float*)d_in[6];
  const float* lin_b = (const float*)d_in[7];
  const float* w1g = (const float*)d_in[8];
  const float* w1bn = (const float*)d_in[9];
  const float* w1w = (const float*)d_in[10];
  const float* w1b = (const float*)d_in[11];
  const float* w2g = (const float*)d_in[12];
  const float* w2bn = (const float*)d_in[13];
  const float* w2w = (const float*)d_in[14];
  const float* w2b = (const float*)d_in[15];
  const float* wg = (const float*)d_in[16];
  const float* wbn = (const float*)d_in[17];
  const float* ww = (const float*)d_in[18];
  const float* wb = (const float*)d_in[19];
  const float* cw1 = (const float*)d_in[20];
  const float* cb1 = (const float*)d_in[21];
  const float* cg = (const float*)d_in[22];
  const float* cbn = (const float*)d_in[23];
  const float* cw2 = (const float*)d_in[24];
  const float* cb2 = (const float*)d_in[25];

  char* p = (char*)d_ws;
  auto alloc = [&](size_t bytes) {
    char* r = p;
    p += (bytes + 255) & ~(size_t)255;
    return r;
  };
  float* X = (float*)alloc((size_t)NN * 128 * 4);
  float* X0 = (float*)alloc((size_t)NN * 128 * 4);
  float* B = (float*)alloc((size_t)NN * 128 * 4);
  float* Qb = (float*)alloc((size_t)NN * 128 * 4);
  float* Xe = (float*)alloc((size_t)NH * 128 * 4);
  float* sn = (float*)alloc((size_t)NN * 4);
  float* qn = (float*)alloc((size_t)NN * 4);
  float* se = (float*)alloc((size_t)NH * 4);
  float* qe = (float*)alloc((size_t)NH * 4);
  float* suma = (float*)alloc((size_t)NN * 4);
  float* invdeg = (float*)alloc((size_t)NN * 4);
  float* t2arr = (float*)alloc((size_t)NN * 4);
  int* starts_e_all = (int*)alloc((size_t)2 * (NH + 1) * 4);
  int* starts_v_all = (int*)alloc((size_t)2 * (NN + 1) * 4);
  int* cursor_all = (int*)alloc((size_t)2 * NH * 4);
  int* bsums_all = (int*)alloc((size_t)2 * 1024 * 4);
  int* v_by_e1 = (int*)alloc((size_t)NI * 4);
  int* v_by_e2 = (int*)alloc((size_t)NI * 4);
  int* e_by_v1 = (int*)alloc((size_t)NI * 4);
  int* e_by_v2 = (int*)alloc((size_t)NI * 4);
  float* W2g = (float*)alloc((size_t)256 * 128 * 4);
  float* s_g = (float*)alloc(128 * 4);
  float* c0 = (float*)alloc(128 * 4);

  int* se1 = starts_e_all;
  int* se2 = starts_e_all + (NH + 1);
  int* sv1 = starts_v_all;
  int* sv2 = starts_v_all + (NN + 1);
  int* cur1 = cursor_all;
  int* cur2 = cursor_all + NH;
  int* bs1 = bsums_all;
  int* bs2 = bsums_all + 1024;

  // W2 precompute (shared by both branches)
  k_prep_w2g<<<128, 256, 0, stream>>>(w2w, w2g, W2g);
  k_prep_sgc0<<<1, 128, 0, stream>>>(w2w, w2g, w2bn, w2b, s_g, c0);

  const int GBI = (NI + 255) / 256;
  const int GBE = (NH + 1023) / 1024;
  const int GBV = (NN + 1023) / 1024;
  const int GHE = (NH + 255) / 256;
  const int GHV = (NN + 255) / 256;

  // ---- CSR by hedge, both branches ----
  hipMemsetAsync(starts_e_all, 0, (size_t)2 * (NH + 1) * 4, stream);
  k_hist2<<<2 * GBI, 256, 0, stream>>>(e1, e2, NI, se1, se2);
  k_scan1_2<<<2 * GBE, 1024, 0, stream>>>(se1, se2, NH, bs1, bs2);
  k_scan2_2<<<2, 1024, 0, stream>>>(bs1, bs2, GBE);
  k_scan3_2<<<2 * GHE, 256, 0, stream>>>(se1, se2, bs1, bs2, NH, NI);
  hipMemsetAsync(cursor_all, 0, (size_t)2 * NH * 4, stream);
  k_fill2<<<2 * GBI, 256, 0, stream>>>(e1, v1, e2, v2, NI, se1, se2, cur1, cur2,
                                       v_by_e1, v_by_e2);
  k_sort2<<<2 * GHE, 256, 0, stream>>>(se1, se2, NH, v_by_e1, v_by_e2);
  // ---- CSR by node, both branches ----
  hipMemsetAsync(starts_v_all, 0, (size_t)2 * (NN + 1) * 4, stream);
  k_hist2<<<2 * GBI, 256, 0, stream>>>(v1, v2, NI, sv1, sv2);
  k_scan1_2<<<2 * GBV, 1024, 0, stream>>>(sv1, sv2, NN, bs1, bs2);
  k_scan2_2<<<2, 1024, 0, stream>>>(bs1, bs2, GBV);
  k_scan3_2<<<2 * GHV, 256, 0, stream>>>(sv1, sv2, bs1, bs2, NN, NI);
  hipMemsetAsync(cursor_all, 0, (size_t)2 * NH * 4, stream);
  k_fill2<<<2 * GBI, 256, 0, stream>>>(v1, e1, v2, e2, NI, sv1, sv2, cur1, cur2,
                                       e_by_v1, e_by_v2);
  k_sort2<<<2 * GHV, 256, 0, stream>>>(sv1, sv2, NN, e_by_v1, e_by_v2);

  float* out = (float*)d_out;
  run_branch(x1, lin_w, lin_b, w1g, w1bn, w1w, w1b, W2g, s_g, c0,
             wg, wbn, ww, wb, cw1, cb1, cg, cbn, cw2, cb2,
             X, X0, B, Qb, Xe, sn, qn, se, qe, suma, invdeg, t2arr,
             se1, sv1, v_by_e1, e_by_v1, out, stream);
  run_branch(x2, lin_w, lin_b, w1g, w1bn, w1w, w1b, W2g, s_g, c0,
             wg, wbn, ww, wb, cw1, cb1, cg, cbn, cw2, cb2,
             X, X0, B, Qb, Xe, sn, qn, se, qe, suma, invdeg, t2arr,
             se2, sv2, v_by_e2, e_by_v2, out + NN, stream);
}